// Round 8
// baseline (75.580 us; speedup 1.0000x reference)
//
#include <hip/hip_runtime.h>

// R8 = R5 kernel, DISPATCHED TWICE (diagnostic round).
// Second dispatch rewrites identical values (idempotent, deterministic).
// Purpose: separate device time from graph-replay overhead:
//   dev = T(R8) - T(R5),  overhead = 2*T(R5) - T(R8).
//
// out[b, n*7+c, w] = sum_k x[b, w*3+k-21, c] * kern[n, k]   (n in 0..72)
// out[b, 511,   w] = sum_k x[b, w*3+k-21, 0] * kern[73, k]

typedef float f32x4 __attribute__((ext_vector_type(4)));

constexpr int Bn   = 32;
constexpr int Sn   = 8192;
constexpr int Cn   = 7;
constexpr int Kn   = 8;
constexpr int PADn = 21;
constexpr int Wn   = 2736;          // (8192+21-8)/3 + 1
constexpr int OCH  = 512;           // 73*7 + 1
constexpr int NCH  = 684;           // float4 chunks per row
constexpr int CHT  = 64;            // chunks per block tile (256 w) -> 1KB, 64B-aligned bursts
constexpr int NWQ  = 11;            // ceil(684/64)
constexpr int SAMP = 773;           // samples per tile: (256-1)*3 + 8
constexpr int CSTR = 776;           // per-channel LDS stride (>=773, mult of 4)

__global__ __launch_bounds__(256)
void conv_v5(const float* __restrict__ x, const float* __restrict__ kern,
             float* __restrict__ out) {
    __shared__ float lx[Cn * CSTR];      // 21.7 KB -> 7 blocks/CU

    const int tid = threadIdx.x;
    const int wq  = blockIdx.x;          // 0..10  (w-tile)
    const int gp  = blockIdx.y;          // 0..1   (n-half)
    const int b   = blockIdx.z;          // 0..31

    const int sbase = wq * 768 - PADn;
    const int g0    = sbase * Cn;
    const float* xb = x + (size_t)b * Sn * Cn;
    for (int i = tid; i < SAMP * Cn; i += 256) {
        int gg = g0 + i;
        float v = (gg >= 0 && gg < Sn * Cn) ? xb[gg] : 0.0f;
        int s = i / 7;
        int c = i - 7 * s;
        lx[c * CSTR + s] = v;
    }
    __syncthreads();

    const int lane  = tid & 63;
    const int r     = __builtin_amdgcn_readfirstlane(tid >> 6);  // wave 0..3
    const int chunk = wq * CHT + lane;
    if (chunk >= NCH) return;

    const int n0 = gp ? 36 : 0;
    const int n1 = gp ? 73 : 36;

    float* ob = out + (size_t)b * OCH * Wn + 4 * chunk;
    const int sloc = 12 * lane;

    for (int c = 0; c < Cn; ++c) {
        const float* lr = lx + c * CSTR + sloc;
        float xw[17];
        *reinterpret_cast<f32x4*>(xw + 0)  = *reinterpret_cast<const f32x4*>(lr + 0);
        *reinterpret_cast<f32x4*>(xw + 4)  = *reinterpret_cast<const f32x4*>(lr + 4);
        *reinterpret_cast<f32x4*>(xw + 8)  = *reinterpret_cast<const f32x4*>(lr + 8);
        *reinterpret_cast<f32x4*>(xw + 12) = *reinterpret_cast<const f32x4*>(lr + 12);
        xw[16] = lr[16];

        for (int n = n0 + r; n < n1; n += 4) {
            const float* kr = kern + n * Kn;
            float a0 = 0.f, a1 = 0.f, a2 = 0.f, a3 = 0.f;
#pragma unroll
            for (int k = 0; k < 8; ++k) {
                float kv = kr[k];
                a0 = fmaf(xw[0 + k], kv, a0);
                a1 = fmaf(xw[3 + k], kv, a1);
                a2 = fmaf(xw[6 + k], kv, a2);
                a3 = fmaf(xw[9 + k], kv, a3);
            }
            f32x4 o = {a0, a1, a2, a3};
            *reinterpret_cast<f32x4*>(ob + (size_t)(n * 7 + c) * Wn) = o;
        }
        if (c == 0 && gp == 1 && r == 3) {
            const float* kr = kern + 73 * Kn;
            float a0 = 0.f, a1 = 0.f, a2 = 0.f, a3 = 0.f;
#pragma unroll
            for (int k = 0; k < 8; ++k) {
                float kv = kr[k];
                a0 = fmaf(xw[0 + k], kv, a0);
                a1 = fmaf(xw[3 + k], kv, a1);
                a2 = fmaf(xw[6 + k], kv, a2);
                a3 = fmaf(xw[9 + k], kv, a3);
            }
            f32x4 o = {a0, a1, a2, a3};
            *reinterpret_cast<f32x4*>(ob + (size_t)511 * Wn) = o;
        }
    }
}

extern "C" void kernel_launch(void* const* d_in, const int* in_sizes, int n_in,
                              void* d_out, int out_size, void* d_ws, size_t ws_size,
                              hipStream_t stream) {
    const float* x    = (const float*)d_in[0];
    const float* kern = (const float*)d_in[1];
    float* out        = (float*)d_out;

    // Diagnostic: two identical dispatches (idempotent).
    conv_v5<<<dim3(NWQ, 2, Bn), 256, 0, stream>>>(x, kern, out);
    conv_v5<<<dim3(NWQ, 2, Bn), 256, 0, stream>>>(x, kern, out);
}

// Round 9
// 38.259 us; speedup vs baseline: 1.9755x; 1.9755x over previous
//
#include <hip/hip_runtime.h>

// out[b, n*7+c, w] = sum_k x[b, w*3+k-21, c] * kern[n, k]   (n in 0..72)
// out[b, 511,   w] = sum_k x[b, w*3+k-21, 0] * kern[73, k]
// Output (32, 512, 2736) fp32.
//
// R9 = R5 structure with exact CU balance:
//   grid (12 wq, 2 gp, 32 b) = 768 blocks = exactly 3 per CU.
//   684 float4-chunks split: wq<3 -> 60 chunks, else 56 (all mult of 4
//   -> every tile base / wave store burst is 64B-aligned; R7's bug avoided).
//   Everything else identical to R5 (plain stores, LDS per-channel rows,
//   wave-row-uniform n striping).

typedef float f32x4 __attribute__((ext_vector_type(4)));

constexpr int Bn   = 32;
constexpr int Sn   = 8192;
constexpr int Cn   = 7;
constexpr int Kn   = 8;
constexpr int PADn = 21;
constexpr int Wn   = 2736;          // (8192+21-8)/3 + 1
constexpr int OCH  = 512;           // 73*7 + 1
constexpr int MAXCH = 60;           // max chunks per tile
constexpr int SAMP = (MAXCH - 1) * 12 + 17;   // 725 samples (CHT=60 tile)
constexpr int CSTR = 728;           // per-channel LDS stride (mult of 4)

__global__ __launch_bounds__(256)
void conv_v9(const float* __restrict__ x, const float* __restrict__ kern,
             float* __restrict__ out) {
    __shared__ float lx[Cn * CSTR];      // 20.4 KB -> 3 blocks/CU easily

    const int tid = threadIdx.x;
    const int wq  = blockIdx.x;          // 0..11  (w-tile)
    const int gp  = blockIdx.y;          // 0..1   (n-half)
    const int b   = blockIdx.z;          // 0..31

    // tile geometry: wq<3 -> 60 chunks, else 56; prefix offset in chunks
    const int cht  = 56 + ((wq < 3) ? 4 : 0);
    const int coff = 56 * wq + 4 * ((wq < 3) ? wq : 3);
    const int samp = (cht - 1) * 12 + 17;

    // ---- stage: dense coalesced global reads -> per-channel LDS rows ----
    const int g0 = (12 * coff - PADn) * Cn;   // first float of tile region
    const float* xb = x + (size_t)b * Sn * Cn;
    for (int i = tid; i < samp * Cn; i += 256) {
        int gg = g0 + i;
        float v = (gg >= 0 && gg < Sn * Cn) ? xb[gg] : 0.0f;
        int s = i / 7;
        int c = i - 7 * s;
        lx[c * CSTR + s] = v;
    }
    __syncthreads();

    const int lane = tid & 63;
    const int r    = __builtin_amdgcn_readfirstlane(tid >> 6);   // wave 0..3
    if (lane >= cht) return;             // lanes beyond tile idle (<=12%)

    const int n0 = gp ? 36 : 0;
    const int n1 = gp ? 73 : 36;

    float* ob = out + (size_t)b * OCH * Wn + 4 * (coff + lane);
    const int sloc = 12 * lane;          // window start sample (local)

    for (int c = 0; c < Cn; ++c) {
        const float* lr = lx + c * CSTR + sloc;
        float xw[17];
        *reinterpret_cast<f32x4*>(xw + 0)  = *reinterpret_cast<const f32x4*>(lr + 0);
        *reinterpret_cast<f32x4*>(xw + 4)  = *reinterpret_cast<const f32x4*>(lr + 4);
        *reinterpret_cast<f32x4*>(xw + 8)  = *reinterpret_cast<const f32x4*>(lr + 8);
        *reinterpret_cast<f32x4*>(xw + 12) = *reinterpret_cast<const f32x4*>(lr + 12);
        xw[16] = lr[16];

        for (int n = n0 + r; n < n1; n += 4) {   // wave-uniform rows
            const float* kr = kern + n * Kn;
            float a0 = 0.f, a1 = 0.f, a2 = 0.f, a3 = 0.f;
#pragma unroll
            for (int k = 0; k < 8; ++k) {
                float kv = kr[k];
                a0 = fmaf(xw[0 + k], kv, a0);
                a1 = fmaf(xw[3 + k], kv, a1);
                a2 = fmaf(xw[6 + k], kv, a2);
                a3 = fmaf(xw[9 + k], kv, a3);
            }
            f32x4 o = {a0, a1, a2, a3};
            *reinterpret_cast<f32x4*>(ob + (size_t)(n * 7 + c) * Wn) = o;
        }
        if (c == 0 && gp == 1 && r == 3) {       // row 511 (kern 73, ch 0)
            const float* kr = kern + 73 * Kn;
            float a0 = 0.f, a1 = 0.f, a2 = 0.f, a3 = 0.f;
#pragma unroll
            for (int k = 0; k < 8; ++k) {
                float kv = kr[k];
                a0 = fmaf(xw[0 + k], kv, a0);
                a1 = fmaf(xw[3 + k], kv, a1);
                a2 = fmaf(xw[6 + k], kv, a2);
                a3 = fmaf(xw[9 + k], kv, a3);
            }
            f32x4 o = {a0, a1, a2, a3};
            *reinterpret_cast<f32x4*>(ob + (size_t)511 * Wn) = o;
        }
    }
}

extern "C" void kernel_launch(void* const* d_in, const int* in_sizes, int n_in,
                              void* d_out, int out_size, void* d_ws, size_t ws_size,
                              hipStream_t stream) {
    const float* x    = (const float*)d_in[0];
    const float* kern = (const float*)d_in[1];
    float* out        = (float*)d_out;

    conv_v9<<<dim3(12, 2, Bn), 256, 0, stream>>>(x, kern, out);
}